// Round 5
// baseline (168.895 us; speedup 1.0000x reference)
//
#include <hip/hip_runtime.h>

// x = (B,1,1024,1024) fp32. Pre-CLAHE chain collapses exactly to
// (x - min)/(max - min). 3 dispatches:
//  k_tilestat: per-tile block reads tile into regs -> tile min/max partials
//              -> 2048-bin fine hist over the TILE's own range (LDS) -> u16 out
//  k_lut:      reduce partials -> global mn/inv; re-bin fine(2048,tile range)
//              -> coarse(256,global range) by bin-center; clip/scan -> LUT;
//              block0 writes gmm + y tail
//  k_apply:    8-row strips; interleaved (l0,l1) float2 LUT in LDS (b64
//              gathers); exact bins recomputed from x; float4 out
// ws: partials float2[T] @0 ; gmm float2 @8192 ; fineh u16[T][2048] @16384 ;
//     lut f32[T][256] after. (T = B*64 tiles)

#define BINS 256
#define FBINS 2048
#define MAXV 2560u        // int(40 * 16384 / 256)

__global__ __launch_bounds__(256) void k_tilestat(const float* __restrict__ x,
                                                  float2* __restrict__ partials,
                                                  unsigned* __restrict__ finehg){
  __shared__ unsigned fh[FBINS];
  __shared__ float smin[4], smax[4];
  __shared__ float sp[2];
  int t = threadIdx.x;
  int tile = blockIdx.x;
  int bc = tile >> 6, ti = (tile >> 3) & 7, tj = tile & 7;
  const float4* x4 = (const float4*)(x + ((size_t)bc * 1024 + ti * 128) * 1024 + tj * 128);
  float4 v[16];
  #pragma unroll
  for (int k = 0; k < 16; k++){
    int p = t + (k << 8);              // 32 float4 per 128-px row
    v[k] = x4[(p >> 5) * 256 + (p & 31)];
  }
  #pragma unroll
  for (int i = 0; i < FBINS / 256; i++) fh[t + i * 256] = 0u;
  float lmin = INFINITY, lmax = -INFINITY;
  #pragma unroll
  for (int k = 0; k < 16; k++){
    lmin = fminf(lmin, fminf(fminf(v[k].x, v[k].y), fminf(v[k].z, v[k].w)));
    lmax = fmaxf(lmax, fmaxf(fmaxf(v[k].x, v[k].y), fmaxf(v[k].z, v[k].w)));
  }
  for (int o = 32; o > 0; o >>= 1){
    lmin = fminf(lmin, __shfl_down(lmin, o, 64));
    lmax = fmaxf(lmax, __shfl_down(lmax, o, 64));
  }
  int lane = t & 63, wv = t >> 6;
  if (lane == 0){ smin[wv] = lmin; smax[wv] = lmax; }
  __syncthreads();
  if (t == 0){
    float m = smin[0], M = smax[0];
    #pragma unroll
    for (int i = 1; i < 4; i++){ m = fminf(m, smin[i]); M = fmaxf(M, smax[i]); }
    partials[tile] = make_float2(m, M);
    sp[0] = m;
    sp[1] = (float)FBINS / fmaxf(M - m, 1e-30f);
  }
  __syncthreads();
  float tmn = sp[0], tinv = sp[1];
  #pragma unroll 4
  for (int k = 0; k < 16; k++){
    int b0 = min((int)((v[k].x - tmn) * tinv), FBINS - 1);
    int b1 = min((int)((v[k].y - tmn) * tinv), FBINS - 1);
    int b2 = min((int)((v[k].z - tmn) * tinv), FBINS - 1);
    int b3 = min((int)((v[k].w - tmn) * tinv), FBINS - 1);
    atomicAdd(&fh[b0], 1u);
    atomicAdd(&fh[b1], 1u);
    atomicAdd(&fh[b2], 1u);
    atomicAdd(&fh[b3], 1u);
  }
  __syncthreads();
  unsigned* outp = finehg + (size_t)tile * (FBINS / 2);
  #pragma unroll
  for (int i = 0; i < FBINS / 512; i++){     // 1024 packed words, 4/thread
    int w = t + i * 256;
    outp[w] = (fh[2 * w] & 0xFFFFu) | (fh[2 * w + 1] << 16);
  }
}

__global__ __launch_bounds__(256) void k_lut(const float2* __restrict__ partials,
                                             int nparts,
                                             const unsigned* __restrict__ finehg,
                                             float* __restrict__ lut,
                                             float2* __restrict__ gmm,
                                             const int* __restrict__ y,
                                             float* __restrict__ out,
                                             int N, int tail){
  __shared__ unsigned ch[BINS];
  __shared__ unsigned sc[BINS];
  __shared__ unsigned wsum[4];
  __shared__ float smin[4], smax[4];
  __shared__ float sp[2];
  int t = threadIdx.x;
  int tile = blockIdx.x;
  ch[t] = 0u;
  float lmin = INFINITY, lmax = -INFINITY;
  for (int i = t; i < nparts; i += 256){
    float2 p = partials[i];
    lmin = fminf(lmin, p.x);
    lmax = fmaxf(lmax, p.y);
  }
  for (int o = 32; o > 0; o >>= 1){
    lmin = fminf(lmin, __shfl_down(lmin, o, 64));
    lmax = fmaxf(lmax, __shfl_down(lmax, o, 64));
  }
  int lane = t & 63, wv = t >> 6;
  if (lane == 0){ smin[wv] = lmin; smax[wv] = lmax; }
  __syncthreads();
  if (t == 0){
    float m = smin[0], M = smax[0];
    #pragma unroll
    for (int i = 1; i < 4; i++){ m = fminf(m, smin[i]); M = fmaxf(M, smax[i]); }
    sp[0] = m;
    sp[1] = 1.0f / (M - m);
  }
  __syncthreads();
  float mn = sp[0], inv = sp[1];
  float2 tp = partials[tile];
  float tw = (tp.y - tp.x) * (1.0f / (float)FBINS);
  const unsigned* fhp = finehg + (size_t)tile * (FBINS / 2);
  #pragma unroll
  for (int i = 0; i < 4; i++){
    int w = t + i * 256;
    unsigned pk = fhp[w];
    unsigned c0 = pk & 0xFFFFu, c1 = pk >> 16;
    int f0 = 2 * w;
    if (c0){
      float ctr = tp.x + ((float)f0 + 0.5f) * tw;
      int cb = min(max((int)(((ctr - mn) * inv) * 256.0f), 0), 255);
      atomicAdd(&ch[cb], c0);
    }
    if (c1){
      float ctr = tp.x + ((float)f0 + 1.5f) * tw;
      int cb = min(max((int)(((ctr - mn) * inv) * 256.0f), 0), 255);
      atomicAdd(&ch[cb], c1);
    }
  }
  __syncthreads();
  unsigned h = ch[t];
  if (h > MAXV) h = MAXV;
  unsigned s = h;
  for (int o = 32; o > 0; o >>= 1) s += __shfl_down(s, o, 64);
  if (lane == 0) wsum[wv] = s;
  __syncthreads();
  unsigned total = wsum[0] + wsum[1] + wsum[2] + wsum[3];
  float residual = (16384.0f - (float)total) * (1.0f / 256.0f);
  sc[t] = h;
  __syncthreads();
  for (int o = 1; o < 256; o <<= 1){
    unsigned pv = (t >= o) ? sc[t - o] : 0u;
    __syncthreads();
    sc[t] += pv;
    __syncthreads();
  }
  float cum = ((float)sc[t] + (float)(t + 1) * residual) * (255.0f / 16384.0f);
  lut[(size_t)tile * BINS + t] = floorf(fminf(fmaxf(cum, 0.0f), 255.0f));
  if (tile == 0){
    if (t == 0) *gmm = make_float2(mn, inv);
    if (t < tail) out[N + t] = (float)y[t];
  }
}

// one block = 8-row strip (i0/i1 uniform: band boundaries 64+128k are 8-aligned)
__global__ __launch_bounds__(256) void k_apply(const float* __restrict__ x,
                                               const float2* __restrict__ gmm,
                                               const float* __restrict__ lutg,
                                               float* __restrict__ out){
  __shared__ float2 lint[2048];     // (l0,l1) interleaved, 16 KB
  int t = threadIdx.x;
  int strip = blockIdx.x;
  int b = strip >> 7;
  int r0 = (strip & 127) << 3;
  float gi = fminf(fmaxf((r0 + 0.5f) * (1.0f / 128.0f) - 0.5f, 0.0f), 7.0f);
  int i0 = (int)gi;
  int i1 = min(i0 + 1, 7);
  const float* g0 = lutg + ((size_t)b * 8 + i0) * 2048;
  const float* g1 = lutg + ((size_t)b * 8 + i1) * 2048;
  #pragma unroll
  for (int i = 0; i < 8; i++){
    int k = t + i * 256;
    lint[k] = make_float2(g0[k], g1[k]);
  }
  float2 mmv = *gmm;
  float mn = mmv.x, inv = mmv.y;
  int j0[4], j1[4];
  float wx[4];
  #pragma unroll
  for (int c = 0; c < 4; c++){
    int col = (t << 2) + c;
    float gj = fminf(fmaxf((col + 0.5f) * (1.0f / 128.0f) - 0.5f, 0.0f), 7.0f);
    j0[c] = (int)gj;
    j1[c] = min(j0[c] + 1, 7);
    wx[c] = gj - (float)j0[c];
  }
  size_t base4 = ((size_t)b * 1024 + r0) * 256;   // float4 units
  __syncthreads();
  for (int r = 0; r < 8; r++){
    int h = r0 + r;
    float giw = fminf(fmaxf((h + 0.5f) * (1.0f / 128.0f) - 0.5f, 0.0f), 7.0f);
    float wy = giw - (float)i0;
    float4 xv = ((const float4*)x)[base4 + r * 256 + t];
    int bi[4];
    bi[0] = min(max((int)(((xv.x - mn) * inv) * 256.0f), 0), 255);
    bi[1] = min(max((int)(((xv.y - mn) * inv) * 256.0f), 0), 255);
    bi[2] = min(max((int)(((xv.z - mn) * inv) * 256.0f), 0), 255);
    bi[3] = min(max((int)(((xv.w - mn) * inv) * 256.0f), 0), 255);
    float res[4];
    #pragma unroll
    for (int c = 0; c < 4; c++){
      float2 p0 = lint[(j0[c] << 8) + bi[c]];   // (v00, v10)
      float2 p1 = lint[(j1[c] << 8) + bi[c]];   // (v01, v11)
      float top = p0.x + wx[c] * (p1.x - p0.x);
      float bot = p0.y + wx[c] * (p1.y - p0.y);
      res[c] = (top + wy * (bot - top)) * (1.0f / 255.0f);
    }
    ((float4*)out)[base4 + r * 256 + t] = make_float4(res[0], res[1], res[2], res[3]);
  }
}

extern "C" void kernel_launch(void* const* d_in, const int* in_sizes, int n_in,
                              void* d_out, int out_size, void* d_ws, size_t ws_size,
                              hipStream_t stream){
  const float* x = (const float*)d_in[0];
  const int* y = (const int*)d_in[1];
  float* out = (float*)d_out;
  int N = in_sizes[0];
  int B = N >> 20;
  int T = B * 64;
  float2* partials = (float2*)d_ws;
  float2* gmm = (float2*)((char*)d_ws + 8192);
  unsigned* fineh = (unsigned*)((char*)d_ws + 16384);
  float* lut = (float*)((char*)d_ws + 16384 + (size_t)T * (FBINS * 2));
  int tail = out_size - N;

  hipLaunchKernelGGL(k_tilestat, dim3(T), dim3(256), 0, stream, x, partials, fineh);
  hipLaunchKernelGGL(k_lut, dim3(T), dim3(256), 0, stream,
                     partials, T, fineh, lut, gmm, y, out, N, tail);
  hipLaunchKernelGGL(k_apply, dim3(B * 128), dim3(256), 0, stream,
                     x, gmm, lut, out);
}

// Round 6
// 131.352 us; speedup vs baseline: 1.2858x; 1.2858x over previous
//
#include <hip/hip_runtime.h>

// x = (B,1,1024,1024) fp32. Pre-CLAHE chain collapses exactly to
// (x - min)/(max - min). 3 dispatches:
//  k_tilestat: per-tile block reads tile into REGISTERS (all loops FULLY
//              unrolled — any partial unroll dynamic-indexes v[] and spills
//              64 MB to scratch, the round-3/round-5 regression) ->
//              tile min/max partials -> 2048-bin fine hist over the tile's
//              own range (LDS) -> packed u16 out
//  k_lut:      reduce partials -> global mn/inv; re-bin fine(2048,tile range)
//              -> coarse(256,global range) by bin-center; clip/scan -> LUT;
//              block0 writes gmm + y tail
//  k_apply:    8-row strips; interleaved (l0,l1) float2 LUT in LDS (b64
//              gathers); exact bins recomputed from x (L3-hot); float4 out
// ws: partials float2[T] @0 ; gmm float2 @8192 ; fineh u16[T][2048] @16384 ;
//     lut f32[T][256] after. (T = B*64 tiles)

#define BINS 256
#define FBINS 2048
#define MAXV 2560u        // int(40 * 16384 / 256)

__global__ __launch_bounds__(256, 4) void k_tilestat(const float* __restrict__ x,
                                                     float2* __restrict__ partials,
                                                     unsigned* __restrict__ finehg){
  __shared__ unsigned fh[FBINS];
  __shared__ float smin[4], smax[4];
  __shared__ float sp[2];
  int t = threadIdx.x;
  int tile = blockIdx.x;
  int bc = tile >> 6, ti = (tile >> 3) & 7, tj = tile & 7;
  const float4* x4 = (const float4*)(x + ((size_t)bc * 1024 + ti * 128) * 1024 + tj * 128);
  float4 v[16];
  #pragma unroll
  for (int k = 0; k < 16; k++){
    int p = t + (k << 8);              // 32 float4 per 128-px row
    v[k] = x4[(p >> 5) * 256 + (p & 31)];
  }
  #pragma unroll
  for (int i = 0; i < FBINS / 256; i++) fh[t + i * 256] = 0u;
  float lmin = INFINITY, lmax = -INFINITY;
  #pragma unroll
  for (int k = 0; k < 16; k++){
    lmin = fminf(lmin, fminf(fminf(v[k].x, v[k].y), fminf(v[k].z, v[k].w)));
    lmax = fmaxf(lmax, fmaxf(fmaxf(v[k].x, v[k].y), fmaxf(v[k].z, v[k].w)));
  }
  for (int o = 32; o > 0; o >>= 1){
    lmin = fminf(lmin, __shfl_down(lmin, o, 64));
    lmax = fmaxf(lmax, __shfl_down(lmax, o, 64));
  }
  int lane = t & 63, wv = t >> 6;
  if (lane == 0){ smin[wv] = lmin; smax[wv] = lmax; }
  __syncthreads();
  if (t == 0){
    float m = smin[0], M = smax[0];
    #pragma unroll
    for (int i = 1; i < 4; i++){ m = fminf(m, smin[i]); M = fmaxf(M, smax[i]); }
    partials[tile] = make_float2(m, M);
    sp[0] = m;
    sp[1] = (float)FBINS / fmaxf(M - m, 1e-30f);
  }
  __syncthreads();
  float tmn = sp[0], tinv = sp[1];
  #pragma unroll          // FULL unroll: constant v[k] indices, no scratch
  for (int k = 0; k < 16; k++){
    int b0 = min((int)((v[k].x - tmn) * tinv), FBINS - 1);
    int b1 = min((int)((v[k].y - tmn) * tinv), FBINS - 1);
    int b2 = min((int)((v[k].z - tmn) * tinv), FBINS - 1);
    int b3 = min((int)((v[k].w - tmn) * tinv), FBINS - 1);
    atomicAdd(&fh[b0], 1u);
    atomicAdd(&fh[b1], 1u);
    atomicAdd(&fh[b2], 1u);
    atomicAdd(&fh[b3], 1u);
  }
  __syncthreads();
  unsigned* outp = finehg + (size_t)tile * (FBINS / 2);
  #pragma unroll
  for (int i = 0; i < FBINS / 512; i++){     // 1024 packed words, 4/thread
    int w = t + i * 256;
    outp[w] = (fh[2 * w] & 0xFFFFu) | (fh[2 * w + 1] << 16);
  }
}

__global__ __launch_bounds__(256) void k_lut(const float2* __restrict__ partials,
                                             int nparts,
                                             const unsigned* __restrict__ finehg,
                                             float* __restrict__ lut,
                                             float2* __restrict__ gmm,
                                             const int* __restrict__ y,
                                             float* __restrict__ out,
                                             int N, int tail){
  __shared__ unsigned ch[BINS];
  __shared__ unsigned sc[BINS];
  __shared__ unsigned wsum[4];
  __shared__ float smin[4], smax[4];
  __shared__ float sp[2];
  int t = threadIdx.x;
  int tile = blockIdx.x;
  ch[t] = 0u;
  float lmin = INFINITY, lmax = -INFINITY;
  for (int i = t; i < nparts; i += 256){
    float2 p = partials[i];
    lmin = fminf(lmin, p.x);
    lmax = fmaxf(lmax, p.y);
  }
  for (int o = 32; o > 0; o >>= 1){
    lmin = fminf(lmin, __shfl_down(lmin, o, 64));
    lmax = fmaxf(lmax, __shfl_down(lmax, o, 64));
  }
  int lane = t & 63, wv = t >> 6;
  if (lane == 0){ smin[wv] = lmin; smax[wv] = lmax; }
  __syncthreads();
  if (t == 0){
    float m = smin[0], M = smax[0];
    #pragma unroll
    for (int i = 1; i < 4; i++){ m = fminf(m, smin[i]); M = fmaxf(M, smax[i]); }
    sp[0] = m;
    sp[1] = 1.0f / (M - m);
  }
  __syncthreads();
  float mn = sp[0], inv = sp[1];
  float2 tp = partials[tile];
  float tw = (tp.y - tp.x) * (1.0f / (float)FBINS);
  const unsigned* fhp = finehg + (size_t)tile * (FBINS / 2);
  #pragma unroll
  for (int i = 0; i < 4; i++){
    int w = t + i * 256;
    unsigned pk = fhp[w];
    unsigned c0 = pk & 0xFFFFu, c1 = pk >> 16;
    int f0 = 2 * w;
    if (c0){
      float ctr = tp.x + ((float)f0 + 0.5f) * tw;
      int cb = min(max((int)(((ctr - mn) * inv) * 256.0f), 0), 255);
      atomicAdd(&ch[cb], c0);
    }
    if (c1){
      float ctr = tp.x + ((float)f0 + 1.5f) * tw;
      int cb = min(max((int)(((ctr - mn) * inv) * 256.0f), 0), 255);
      atomicAdd(&ch[cb], c1);
    }
  }
  __syncthreads();
  unsigned h = ch[t];
  if (h > MAXV) h = MAXV;
  unsigned s = h;
  for (int o = 32; o > 0; o >>= 1) s += __shfl_down(s, o, 64);
  if (lane == 0) wsum[wv] = s;
  __syncthreads();
  unsigned total = wsum[0] + wsum[1] + wsum[2] + wsum[3];
  float residual = (16384.0f - (float)total) * (1.0f / 256.0f);
  sc[t] = h;
  __syncthreads();
  for (int o = 1; o < 256; o <<= 1){
    unsigned pv = (t >= o) ? sc[t - o] : 0u;
    __syncthreads();
    sc[t] += pv;
    __syncthreads();
  }
  float cum = ((float)sc[t] + (float)(t + 1) * residual) * (255.0f / 16384.0f);
  lut[(size_t)tile * BINS + t] = floorf(fminf(fmaxf(cum, 0.0f), 255.0f));
  if (tile == 0){
    if (t == 0) *gmm = make_float2(mn, inv);
    if (t < tail) out[N + t] = (float)y[t];
  }
}

// one block = 8-row strip (i0/i1 uniform: band boundaries 64+128k are 8-aligned)
__global__ __launch_bounds__(256) void k_apply(const float* __restrict__ x,
                                               const float2* __restrict__ gmm,
                                               const float* __restrict__ lutg,
                                               float* __restrict__ out){
  __shared__ float2 lint[2048];     // (l0,l1) interleaved, 16 KB
  int t = threadIdx.x;
  int strip = blockIdx.x;
  int b = strip >> 7;
  int r0 = (strip & 127) << 3;
  float gi = fminf(fmaxf((r0 + 0.5f) * (1.0f / 128.0f) - 0.5f, 0.0f), 7.0f);
  int i0 = (int)gi;
  int i1 = min(i0 + 1, 7);
  const float* g0 = lutg + ((size_t)b * 8 + i0) * 2048;
  const float* g1 = lutg + ((size_t)b * 8 + i1) * 2048;
  #pragma unroll
  for (int i = 0; i < 8; i++){
    int k = t + i * 256;
    lint[k] = make_float2(g0[k], g1[k]);
  }
  float2 mmv = *gmm;
  float mn = mmv.x, inv = mmv.y;
  int j0[4], j1[4];
  float wx[4];
  #pragma unroll
  for (int c = 0; c < 4; c++){
    int col = (t << 2) + c;
    float gj = fminf(fmaxf((col + 0.5f) * (1.0f / 128.0f) - 0.5f, 0.0f), 7.0f);
    j0[c] = (int)gj;
    j1[c] = min(j0[c] + 1, 7);
    wx[c] = gj - (float)j0[c];
  }
  size_t base4 = ((size_t)b * 1024 + r0) * 256;   // float4 units
  __syncthreads();
  #pragma unroll
  for (int r = 0; r < 8; r++){
    int h = r0 + r;
    float giw = fminf(fmaxf((h + 0.5f) * (1.0f / 128.0f) - 0.5f, 0.0f), 7.0f);
    float wy = giw - (float)i0;
    float4 xv = ((const float4*)x)[base4 + r * 256 + t];
    int bi[4];
    bi[0] = min(max((int)(((xv.x - mn) * inv) * 256.0f), 0), 255);
    bi[1] = min(max((int)(((xv.y - mn) * inv) * 256.0f), 0), 255);
    bi[2] = min(max((int)(((xv.z - mn) * inv) * 256.0f), 0), 255);
    bi[3] = min(max((int)(((xv.w - mn) * inv) * 256.0f), 0), 255);
    float res[4];
    #pragma unroll
    for (int c = 0; c < 4; c++){
      float2 p0 = lint[(j0[c] << 8) + bi[c]];   // (v00, v10)
      float2 p1 = lint[(j1[c] << 8) + bi[c]];   // (v01, v11)
      float top = p0.x + wx[c] * (p1.x - p0.x);
      float bot = p0.y + wx[c] * (p1.y - p0.y);
      res[c] = (top + wy * (bot - top)) * (1.0f / 255.0f);
    }
    ((float4*)out)[base4 + r * 256 + t] = make_float4(res[0], res[1], res[2], res[3]);
  }
}

extern "C" void kernel_launch(void* const* d_in, const int* in_sizes, int n_in,
                              void* d_out, int out_size, void* d_ws, size_t ws_size,
                              hipStream_t stream){
  const float* x = (const float*)d_in[0];
  const int* y = (const int*)d_in[1];
  float* out = (float*)d_out;
  int N = in_sizes[0];
  int B = N >> 20;
  int T = B * 64;
  float2* partials = (float2*)d_ws;
  float2* gmm = (float2*)((char*)d_ws + 8192);
  unsigned* fineh = (unsigned*)((char*)d_ws + 16384);
  float* lut = (float*)((char*)d_ws + 16384 + (size_t)T * (FBINS * 2));
  int tail = out_size - N;

  hipLaunchKernelGGL(k_tilestat, dim3(T), dim3(256), 0, stream, x, partials, fineh);
  hipLaunchKernelGGL(k_lut, dim3(T), dim3(256), 0, stream,
                     partials, T, fineh, lut, gmm, y, out, N, tail);
  hipLaunchKernelGGL(k_apply, dim3(B * 128), dim3(256), 0, stream,
                     x, gmm, lut, out);
}